// Round 3
// baseline (4811.412 us; speedup 1.0000x reference)
//
#include <hip/hip_runtime.h>
#include <stdint.h>

#define K_IN  4096
#define N_OUT 4096
#define M_TOK 4096

// Runtime-detected element dtype worlds
#define MODE_F16  0
#define MODE_BF16 1
#define MODE_F32  2

static __device__ __forceinline__ float h2f(uint16_t u) {
    union { uint16_t u; _Float16 h; } c; c.u = u; return (float)c.h;
}
static __device__ __forceinline__ float b2f(uint16_t u) {
    union { uint32_t u; float f; } c; c.u = (uint32_t)u << 16; return c.f;
}
static __device__ __forceinline__ uint16_t f2h(float f) {
    union { uint16_t u; _Float16 h; } c; c.h = (_Float16)f; return c.u;
}
static __device__ __forceinline__ uint16_t f2b(float f) {
    union { float f; uint32_t u; } c; c.f = f;
    uint32_t r = c.u + 0x7FFFu + ((c.u >> 16) & 1u);   // RNE
    return (uint16_t)(r >> 16);
}

// ---------------------------------------------------------------------------
// Correctness-bisect kernel: naive tiled VALU GEMM with fused decode.
// Block = 16m x 16n outputs, one thread per output, K-tile = 64.
// LDS tiles padded to stride 68 f32 (bank-conflict-free-enough; 2-way max).
// dtype of input/grid/e81b/output detected at runtime from grid[0] == 0.5:
//   fp16 -> 0x3800, bf16 -> 0x3F00, f32 -> low half 0x0000.
// Code extraction re-implemented independently (byte-offset method).
// ---------------------------------------------------------------------------
__global__ void naive_fused_kernel(const void* __restrict__ Araw,
                                   const uint32_t* __restrict__ Q,
                                   const void* __restrict__ gridraw,
                                   const void* __restrict__ e81braw,
                                   void* __restrict__ Craw)
{
    __shared__ float Alds[16 * 68];
    __shared__ float Wlds[16 * 68];

    const int t  = threadIdx.x;
    const int mi = t >> 4, ni = t & 15;

    const int bid = blockIdx.x;
    const int bm = bid >> 8, bn = bid & 255;
    const size_t mbase = (size_t)bm * 16, nbase = (size_t)bn * 16;

    // ---- dtype detection (grid[0][0] == 0.5 exactly) ----
    uint16_t g0 = ((const uint16_t*)gridraw)[0];
    int mode;
    if (g0 == 0x3800u)      mode = MODE_F16;
    else if (g0 == 0x3F00u) mode = MODE_BF16;
    else                    mode = MODE_F32;

    const float S = 0.49023438f;   // fp16 round of 1/2.04 (exact in bf16/f32)

    // decode-stage mapping: threads 0..127 -> (row, code-in-tile)
    const int drow = t >> 3, dc = t & 7;
    const uint32_t* qrow = Q + (nbase + drow) * 384;

    float acc = 0.0f;

    for (int kt = 0; kt < K_IN / 64; ++kt) {
        const int k0 = kt * 64;

        // ---- A staging: thread loads 4 elems of row (t>>4) ----
        {
            const int ar = t >> 4;
            const int kq = (t & 15) * 4;
            const size_t abase = (mbase + ar) * (size_t)K_IN + k0 + kq;
            float v0, v1, v2, v3;
            if (mode == MODE_F32) {
                float4 f = *(const float4*)((const float*)Araw + abase);
                v0 = f.x; v1 = f.y; v2 = f.z; v3 = f.w;
            } else {
                ushort4 u = *(const ushort4*)((const uint16_t*)Araw + abase);
                if (mode == MODE_F16) { v0 = h2f(u.x); v1 = h2f(u.y); v2 = h2f(u.z); v3 = h2f(u.w); }
                else                  { v0 = b2f(u.x); v1 = b2f(u.y); v2 = b2f(u.z); v3 = b2f(u.w); }
            }
            Alds[ar * 68 + kq + 0] = v0;
            Alds[ar * 68 + kq + 1] = v1;
            Alds[ar * 68 + kq + 2] = v2;
            Alds[ar * 68 + kq + 3] = v3;
        }

        // ---- W decode staging: threads 0..127, one 3-byte code -> 8 weights
        if (t < 128) {
            const int ci  = kt * 8 + dc;          // code index within row [0,512)
            const int byt = ci * 3;
            const int dw  = byt >> 2, off = byt & 3;
            uint32_t w0 = qrow[dw];
            uint32_t w1 = qrow[dw + (off > 1 ? 1 : 0)];   // avoid OOB when not needed
            uint64_t comb = (uint64_t)w0 | ((uint64_t)w1 << 32);
            uint32_t code = (uint32_t)(comb >> (off * 8)) & 0xFFFFFFu;
            uint32_t gi = code >> 8, ri = code & 255u;

            float wv[8];
            if (mode == MODE_F32) {
                const float* gr = (const float*)gridraw + (size_t)gi * 8;
                const float* rr = (const float*)e81braw + (size_t)ri * 8;
                #pragma unroll
                for (int e = 0; e < 8; ++e) wv[e] = gr[e] + S * rr[e];
            } else {
                const uint16_t* gr = (const uint16_t*)gridraw + (size_t)gi * 8;
                const uint16_t* rr = (const uint16_t*)e81braw + (size_t)ri * 8;
                if (mode == MODE_F16) {
                    #pragma unroll
                    for (int e = 0; e < 8; ++e) wv[e] = h2f(gr[e]) + S * h2f(rr[e]);
                } else {
                    #pragma unroll
                    for (int e = 0; e < 8; ++e) wv[e] = b2f(gr[e]) + S * b2f(rr[e]);
                }
            }
            #pragma unroll
            for (int e = 0; e < 8; ++e) Wlds[drow * 68 + dc * 8 + e] = wv[e];
        }
        __syncthreads();

        // ---- MAC: 64 k per tile, float4 LDS reads ----
        #pragma unroll
        for (int q = 0; q < 16; ++q) {
            const float4 av = *(const float4*)&Alds[mi * 68 + q * 4];
            const float4 wv = *(const float4*)&Wlds[ni * 68 + q * 4];
            acc += av.x * wv.x + av.y * wv.y + av.z * wv.z + av.w * wv.w;
        }
        __syncthreads();
    }

    // ---- epilogue in detected dtype ----
    const size_t o = (mbase + mi) * (size_t)N_OUT + nbase + ni;
    if (mode == MODE_F16)       ((uint16_t*)Craw)[o] = f2h(acc);
    else if (mode == MODE_BF16) ((uint16_t*)Craw)[o] = f2b(acc);
    else                        ((float*)Craw)[o]    = acc;
}

extern "C" void kernel_launch(void* const* d_in, const int* in_sizes, int n_in,
                              void* d_out, int out_size, void* d_ws, size_t ws_size,
                              hipStream_t stream) {
    // Map pointers by element count (defensive against ordering assumptions):
    // input 4096*4096=16777216, Qidxs 4096*384=1572864, grid 65536*8=524288,
    // e81b 256*8=2048.
    const void*     A    = d_in[0];
    const uint32_t* Q    = (const uint32_t*)d_in[1];
    const void*     grid = d_in[2];
    const void*     e81b = d_in[3];
    for (int i = 0; i < n_in; ++i) {
        if (in_sizes[i] == 16777216) A    = d_in[i];
        else if (in_sizes[i] == 1572864) Q = (const uint32_t*)d_in[i];
        else if (in_sizes[i] == 524288)  grid = d_in[i];
        else if (in_sizes[i] == 2048)    e81b = d_in[i];
    }

    naive_fused_kernel<<<65536, 256, 0, stream>>>(A, Q, grid, e81b, d_out);
}

// Round 4
// 514.385 us; speedup vs baseline: 9.3537x; 9.3537x over previous
//
#include <hip/hip_runtime.h>
#include <stdint.h>

#define K_IN  4096
#define N_OUT 4096
#define M_TOK 4096

#define MODE_F16  0
#define MODE_BF16 1
#define MODE_F32  2

typedef __attribute__((ext_vector_type(8))) short    bf16x8;
typedef _Float16 f16x8 __attribute__((ext_vector_type(8)));
typedef _Float16 h2    __attribute__((ext_vector_type(2)));
typedef __attribute__((ext_vector_type(4))) float    f32x4;

static __device__ __forceinline__ float bflo(uint32_t u) {
    union { uint32_t u; float f; } c; c.u = u << 16; return c.f;
}
static __device__ __forceinline__ float bfhi(uint32_t u) {
    union { uint32_t u; float f; } c; c.u = u & 0xFFFF0000u; return c.f;
}
static __device__ __forceinline__ uint16_t f2b(float f) {
    union { float f; uint32_t u; } c; c.f = f;
    uint32_t r = c.u + 0x7FFFu + ((c.u >> 16) & 1u);   // RNE
    return (uint16_t)(r >> 16);
}
static __device__ __forceinline__ uint16_t f2h(float f) {
    union { uint16_t u; _Float16 h; } c; c.h = (_Float16)f; return c.u;
}
// packed fp16: w2 = g2 + S2*r2  (v_pk ops; S*r exact for r in {0,+-0.5,+-1,+-2})
static __device__ __forceinline__ uint32_t fma_h2(uint32_t g, uint32_t r, h2 s) {
    union { uint32_t u; h2 h; } G, R, W;
    G.u = g; R.u = r;
    W.h = G.h + s * R.h;
    return W.u;
}
// bf16 pair: f32 math, RNE back (<=1ulp vs double-rounded ref; validated r3)
static __device__ __forceinline__ uint32_t fma_b2(uint32_t g, uint32_t r, float s) {
    float lo = bflo(g) + s * bflo(r);
    float hi = bfhi(g) + s * bfhi(r);
    return (uint32_t)f2b(lo) | ((uint32_t)f2b(hi) << 16);
}

static __device__ __forceinline__ void gload16(const void* g, void* s) {
    __builtin_amdgcn_global_load_lds(
        (const __attribute__((address_space(1))) uint32_t*)g,
        (__attribute__((address_space(3))) uint32_t*)s,
        16, 0, 0);
}

static __device__ __forceinline__ int detect_mode(const void* grid) {
    uint16_t g0 = ((const uint16_t*)grid)[0];   // grid[0][0] == 0.5 exactly
    if (g0 == 0x3800u) return MODE_F16;         // fp16 0.5
    if (g0 == 0x3F00u) return MODE_BF16;        // bf16 0.5
    return MODE_F32;                            // f32 0.5 -> low word 0x0000
}

// ---------------------------------------------------------------------------
// 16-bit worlds (f16 / bf16): fused decode + MFMA GEMM.
// 128x128 tile, BK=64, 4 waves (64x64 each), mfma 16x16x32.
// A: global_load_lds(16B), linear dest, inverse-XOR-swizzled source.
// W: 1 thread = 1 quad (4 codes -> 32 weights), swizzled ds_write_b128.
// Read side undoes the involution (chunk ^= row&7) -> conflict-free b128.
// Decode math & C orientation validated by round-3 naive kernel.
// ---------------------------------------------------------------------------
template<int MODE>
__global__ void fused16(const uint16_t* __restrict__ A,
                        const uint32_t* __restrict__ Q,
                        const uint32_t* __restrict__ grid,   // [65536][8] 16-bit
                        const uint32_t* __restrict__ e81b,   // [256][8] 16-bit
                        uint16_t* __restrict__ C)
{
    if (detect_mode(grid) != MODE) return;      // uniform gate, pre-barrier

    __shared__ uint16_t Alds[128 * 64];
    __shared__ uint16_t Blds[128 * 64];
    __shared__ uint4 e8[256];

    int t = threadIdx.x;
    int l = t & 63, w = t >> 6;

    e8[t] = ((const uint4*)e81b)[t];

    int bid = blockIdx.x;                       // 1024 wgs, bijective XCD swizzle
    int swz = (bid & 7) * 128 + (bid >> 3);
    int bm = swz >> 5, bn = swz & 31;
    size_t mbase = (size_t)bm * 128, nbase = (size_t)bn * 128;

    int lr8 = l >> 3, lc8 = l & 7;
    int l15 = l & 15, lh = l >> 4;
    int wr = w >> 1, wc = w & 1;

    int rB = t >> 1, hB = t & 1;                // decode: row, k-half
    const uint32_t* qrow = Q + (nbase + rB) * 384;
    uint16_t* blds_row = &Blds[rB * 64];
    int r7 = rB & 7;

    h2 s16;
    { union { uint32_t u; h2 h; } c; c.u = 0x37D837D8u; s16 = c.h; }  // fp16(1/2.04)x2
    const float sbf = 0.490234375f;             // bf16(1/2.04), exact in f32

    f32x4 acc[4][4] = {};

    __syncthreads();                            // e8 ready

    for (int kt = 0; kt < K_IN / 64; ++kt) {
        // ---- A staging (async, 16B/lane) ----
        #pragma unroll
        for (int i = 0; i < 4; ++i) {
            int arow = w * 32 + i * 8 + lr8;
            gload16(A + (mbase + arow) * K_IN + kt * 64 + (lc8 ^ (arow & 7)) * 8,
                    &Alds[(w * 32 + i * 8) * 64]);
        }
        // ---- fused W decode: 4 codes -> 32 weights ----
        {
            const uint32_t* src = qrow + kt * 6 + hB * 3;
            uint32_t w0 = src[0], w1 = src[1], w2 = src[2];
            uint32_t code[4] = {
                w0 & 0xFFFFFFu,
                (w0 >> 24) | ((w1 & 0xFFFFu) << 8),
                (w1 >> 16) | ((w2 & 0xFFu) << 16),
                w2 >> 8
            };
            #pragma unroll
            for (int j = 0; j < 4; ++j) {
                uint4 g = ((const uint4*)grid)[code[j] >> 8];
                uint4 r = e8[code[j] & 255];
                uint32_t o[4];
                if constexpr (MODE == MODE_F16) {
                    o[0] = fma_h2(g.x, r.x, s16); o[1] = fma_h2(g.y, r.y, s16);
                    o[2] = fma_h2(g.z, r.z, s16); o[3] = fma_h2(g.w, r.w, s16);
                } else {
                    o[0] = fma_b2(g.x, r.x, sbf); o[1] = fma_b2(g.y, r.y, sbf);
                    o[2] = fma_b2(g.z, r.z, sbf); o[3] = fma_b2(g.w, r.w, sbf);
                }
                int cglob = hB * 4 + j;
                *(uint4*)&blds_row[(cglob ^ r7) * 8] = make_uint4(o[0], o[1], o[2], o[3]);
            }
        }
        __syncthreads();                        // drains vmcnt(0) + lgkm

        // ---- MFMA phase ----
        #pragma unroll
        for (int ks = 0; ks < 2; ++ks) {
            #pragma unroll
            for (int i = 0; i < 4; ++i) {
                int ar = wr * 64 + i * 16 + l15;
                const uint16_t* ap = &Alds[ar * 64 + (((ks << 2) | lh) ^ (ar & 7)) * 8];
                #pragma unroll
                for (int j = 0; j < 4; ++j) {
                    int br = wc * 64 + j * 16 + l15;
                    const uint16_t* bp = &Blds[br * 64 + (((ks << 2) | lh) ^ (br & 7)) * 8];
                    if constexpr (MODE == MODE_F16)
                        acc[i][j] = __builtin_amdgcn_mfma_f32_16x16x32_f16(
                            *(const f16x8*)ap, *(const f16x8*)bp, acc[i][j], 0, 0, 0);
                    else
                        acc[i][j] = __builtin_amdgcn_mfma_f32_16x16x32_bf16(
                            *(const bf16x8*)ap, *(const bf16x8*)bp, acc[i][j], 0, 0, 0);
                }
            }
        }
        __syncthreads();                        // protect LDS reuse
    }

    // epilogue: C/D layout col = lane&15, row = (lane>>4)*4 + reg
    #pragma unroll
    for (int i = 0; i < 4; ++i)
        #pragma unroll
        for (int j = 0; j < 4; ++j) {
            size_t r0 = mbase + wr * 64 + i * 16 + lh * 4;
            size_t c0 = nbase + wc * 64 + j * 16 + l15;
            #pragma unroll
            for (int v = 0; v < 4; ++v) {
                float x = acc[i][j][v];
                C[(r0 + v) * N_OUT + c0] = (MODE == MODE_F16) ? f2h(x) : f2b(x);
            }
        }
}

// ---------------------------------------------------------------------------
// F32 world: same structure, reg-staged A (f32 -> bf16 cvt, swizzled ds_write),
// decode f32 -> bf16, bf16 MFMA, f32 output.
// ---------------------------------------------------------------------------
__global__ void fused32(const float* __restrict__ A,
                        const uint32_t* __restrict__ Q,
                        const float* __restrict__ grid,   // [65536][8] f32
                        const float* __restrict__ e81b,   // [256][8] f32
                        float* __restrict__ C)
{
    if (detect_mode(grid) != MODE_F32) return;

    __shared__ uint16_t Alds[128 * 64];
    __shared__ uint16_t Blds[128 * 64];
    __shared__ float e8f[256 * 8];

    int t = threadIdx.x;
    int l = t & 63, w = t >> 6;

    #pragma unroll
    for (int i = 0; i < 8; ++i) e8f[t * 8 + i] = e81b[t * 8 + i];

    int bid = blockIdx.x;
    int swz = (bid & 7) * 128 + (bid >> 3);
    int bm = swz >> 5, bn = swz & 31;
    size_t mbase = (size_t)bm * 128, nbase = (size_t)bn * 128;

    int lr8 = l >> 3, lc8 = l & 7;
    int l15 = l & 15, lh = l >> 4;
    int wr = w >> 1, wc = w & 1;

    int rB = t >> 1, hB = t & 1;
    const uint32_t* qrow = Q + (nbase + rB) * 384;
    uint16_t* blds_row = &Blds[rB * 64];
    int r7 = rB & 7;
    const float S = 1.0f / 2.04f;

    f32x4 acc[4][4] = {};

    __syncthreads();

    for (int kt = 0; kt < K_IN / 64; ++kt) {
        // ---- A staging: f32 load -> bf16 pack -> swizzled ds_write_b128 ----
        #pragma unroll
        for (int i = 0; i < 4; ++i) {
            int arow = w * 32 + i * 8 + lr8;
            const float* src = A + (mbase + arow) * (size_t)K_IN + kt * 64 + lc8 * 8;
            float4 f0 = ((const float4*)src)[0];
            float4 f1 = ((const float4*)src)[1];
            uint4 o = make_uint4(
                (uint32_t)f2b(f0.x) | ((uint32_t)f2b(f0.y) << 16),
                (uint32_t)f2b(f0.z) | ((uint32_t)f2b(f0.w) << 16),
                (uint32_t)f2b(f1.x) | ((uint32_t)f2b(f1.y) << 16),
                (uint32_t)f2b(f1.z) | ((uint32_t)f2b(f1.w) << 16));
            *(uint4*)&Alds[arow * 64 + (lc8 ^ (arow & 7)) * 8] = o;
        }
        // ---- W decode -> bf16 ----
        {
            const uint32_t* src = qrow + kt * 6 + hB * 3;
            uint32_t w0 = src[0], w1 = src[1], w2 = src[2];
            uint32_t code[4] = {
                w0 & 0xFFFFFFu,
                (w0 >> 24) | ((w1 & 0xFFFFu) << 8),
                (w1 >> 16) | ((w2 & 0xFFu) << 16),
                w2 >> 8
            };
            #pragma unroll
            for (int j = 0; j < 4; ++j) {
                const float* gr = grid + (size_t)(code[j] >> 8) * 8;
                const float* rr = &e8f[(code[j] & 255u) * 8];
                float4 g0 = ((const float4*)gr)[0];
                float4 g1 = ((const float4*)gr)[1];
                float wv[8];
                wv[0] = g0.x + S * rr[0]; wv[1] = g0.y + S * rr[1];
                wv[2] = g0.z + S * rr[2]; wv[3] = g0.w + S * rr[3];
                wv[4] = g1.x + S * rr[4]; wv[5] = g1.y + S * rr[5];
                wv[6] = g1.z + S * rr[6]; wv[7] = g1.w + S * rr[7];
                uint4 o = make_uint4(
                    (uint32_t)f2b(wv[0]) | ((uint32_t)f2b(wv[1]) << 16),
                    (uint32_t)f2b(wv[2]) | ((uint32_t)f2b(wv[3]) << 16),
                    (uint32_t)f2b(wv[4]) | ((uint32_t)f2b(wv[5]) << 16),
                    (uint32_t)f2b(wv[6]) | ((uint32_t)f2b(wv[7]) << 16));
                int cglob = hB * 4 + j;
                *(uint4*)&blds_row[(cglob ^ r7) * 8] = o;
            }
        }
        __syncthreads();

        #pragma unroll
        for (int ks = 0; ks < 2; ++ks) {
            #pragma unroll
            for (int i = 0; i < 4; ++i) {
                int ar = wr * 64 + i * 16 + l15;
                const uint16_t* ap = &Alds[ar * 64 + (((ks << 2) | lh) ^ (ar & 7)) * 8];
                #pragma unroll
                for (int j = 0; j < 4; ++j) {
                    int br = wc * 64 + j * 16 + l15;
                    const uint16_t* bp = &Blds[br * 64 + (((ks << 2) | lh) ^ (br & 7)) * 8];
                    acc[i][j] = __builtin_amdgcn_mfma_f32_16x16x32_bf16(
                        *(const bf16x8*)ap, *(const bf16x8*)bp, acc[i][j], 0, 0, 0);
                }
            }
        }
        __syncthreads();
    }

    #pragma unroll
    for (int i = 0; i < 4; ++i)
        #pragma unroll
        for (int j = 0; j < 4; ++j) {
            size_t r0 = mbase + wr * 64 + i * 16 + lh * 4;
            size_t c0 = nbase + wc * 64 + j * 16 + l15;
            #pragma unroll
            for (int v = 0; v < 4; ++v)
                C[(r0 + v) * N_OUT + c0] = acc[i][j][v];
        }
}

extern "C" void kernel_launch(void* const* d_in, const int* in_sizes, int n_in,
                              void* d_out, int out_size, void* d_ws, size_t ws_size,
                              hipStream_t stream) {
    const void*     A    = d_in[0];
    const uint32_t* Q    = (const uint32_t*)d_in[1];
    const void*     grid = d_in[2];
    const void*     e81b = d_in[3];
    for (int i = 0; i < n_in; ++i) {
        if (in_sizes[i] == 16777216)      A    = d_in[i];
        else if (in_sizes[i] == 1572864)  Q    = (const uint32_t*)d_in[i];
        else if (in_sizes[i] == 524288)   grid = d_in[i];
        else if (in_sizes[i] == 2048)     e81b = d_in[i];
    }

    // Each kernel self-gates on the runtime-detected dtype world; the two
    // non-matching launches exit immediately (~uniform 2B read per block).
    fused16<MODE_F16><<<1024, 256, 0, stream>>>(
        (const uint16_t*)A, Q, (const uint32_t*)grid, (const uint32_t*)e81b,
        (uint16_t*)d_out);
    fused16<MODE_BF16><<<1024, 256, 0, stream>>>(
        (const uint16_t*)A, Q, (const uint32_t*)grid, (const uint32_t*)e81b,
        (uint16_t*)d_out);
    fused32<<<1024, 256, 0, stream>>>(
        (const float*)A, Q, (const float*)grid, (const float*)e81b,
        (float*)d_out);
}

// Round 8
// 269.191 us; speedup vs baseline: 17.8736x; 1.9109x over previous
//
#include <hip/hip_runtime.h>
#include <stdint.h>

#define K_IN  4096
#define N_OUT 4096
#define M_TOK 4096

#define MODE_F16  0
#define MODE_BF16 1
#define MODE_F32  2

typedef __attribute__((ext_vector_type(8))) short    bf16x8;
typedef _Float16 f16x8 __attribute__((ext_vector_type(8)));
typedef _Float16 h2    __attribute__((ext_vector_type(2)));
typedef __attribute__((ext_vector_type(4))) float    f32x4;

static __device__ __forceinline__ float bflo(uint32_t u) {
    union { uint32_t u; float f; } c; c.u = u << 16; return c.f;
}
static __device__ __forceinline__ float bfhi(uint32_t u) {
    union { uint32_t u; float f; } c; c.u = u & 0xFFFF0000u; return c.f;
}
static __device__ __forceinline__ uint16_t f2b(float f) {
    union { float f; uint32_t u; } c; c.f = f;
    uint32_t r = c.u + 0x7FFFu + ((c.u >> 16) & 1u);   // RNE
    return (uint16_t)(r >> 16);
}
static __device__ __forceinline__ uint16_t f2h(float f) {
    union { uint16_t u; _Float16 h; } c; c.h = (_Float16)f; return c.u;
}
static __device__ __forceinline__ uint32_t pk(float a, float b) {
    return (uint32_t)f2b(a) | ((uint32_t)f2b(b) << 16);
}
static __device__ __forceinline__ uint32_t fma_h2(uint32_t g, uint32_t r, h2 s) {
    union { uint32_t u; h2 h; } G, R, W;
    G.u = g; R.u = r;
    W.h = G.h + s * R.h;
    return W.u;
}
static __device__ __forceinline__ uint32_t fma_b2(uint32_t g, uint32_t r, float s) {
    return pk(bflo(g) + s * bflo(r), bfhi(g) + s * bfhi(r));
}

static __device__ __forceinline__ void gload16(const void* g, void* s) {
    __builtin_amdgcn_global_load_lds(
        (const __attribute__((address_space(1))) uint32_t*)g,
        (__attribute__((address_space(3))) uint32_t*)s,
        16, 0, 0);
}

static __device__ __forceinline__ int detect_mode(const void* grid) {
    uint16_t g0 = ((const uint16_t*)grid)[0];   // grid[0][0] == 0.5 exactly
    if (g0 == 0x3800u) return MODE_F16;
    if (g0 == 0x3F00u) return MODE_BF16;
    return MODE_F32;
}

// ===========================================================================
// SPLIT PATH (f32 world, needs 64 MB d_ws)
// ===========================================================================

// A f32 -> bf16 (RNE), 8 floats/thread, coalesced uint4 stores.
__global__ void cvtA_f32(const float* __restrict__ A,
                         const float* __restrict__ grid,
                         uint16_t* __restrict__ Abf)
{
    if (detect_mode(grid) != MODE_F32) return;
    size_t idx = (size_t)blockIdx.x * 256 + threadIdx.x;   // 2097152 threads
    const float4* src = (const float4*)A + idx * 2;
    float4 f0 = src[0], f1 = src[1];
    ((uint4*)Abf)[idx] = make_uint4(pk(f0.x, f0.y), pk(f0.z, f0.w),
                                    pk(f1.x, f1.y), pk(f1.z, f1.w));
}

// One thread = one 3-byte code -> 8 bf16 weights (16B coalesced store).
// Byte-offset extraction validated end-to-end by round-3 naive kernel.
__global__ void decomp_f32(const uint32_t* __restrict__ Q,
                           const float* __restrict__ grid,
                           const float* __restrict__ e81b,
                           uint16_t* __restrict__ W)
{
    if (detect_mode(grid) != MODE_F32) return;
    __shared__ float e8f[2048];
    int t = threadIdx.x;
    #pragma unroll
    for (int i = 0; i < 8; ++i) e8f[t + 256 * i] = e81b[t + 256 * i];
    __syncthreads();

    int ci  = blockIdx.x * 256 + t;            // 2097152 codes
    size_t byt = (size_t)ci * 3;
    int dw = (int)(byt >> 2), off = (int)(byt & 3);
    uint32_t w0 = Q[dw];
    uint32_t w1 = (off > 1) ? Q[dw + 1] : 0u;
    uint32_t code = (uint32_t)(((((uint64_t)w1) << 32) | w0) >> (off * 8)) & 0xFFFFFFu;

    const float4* gr = (const float4*)(grid + (size_t)(code >> 8) * 8);
    const float*  rr = &e8f[(code & 255u) * 8];
    float4 g0 = gr[0], g1 = gr[1];
    const float S = 1.0f / 2.04f;
    ((uint4*)W)[ci] = make_uint4(
        pk(g0.x + S * rr[0], g0.y + S * rr[1]),
        pk(g0.z + S * rr[2], g0.w + S * rr[3]),
        pk(g1.x + S * rr[4], g1.y + S * rr[5]),
        pk(g1.z + S * rr[6], g1.w + S * rr[7]));
}

// m97-structure bf16 BT-GEMM: 128x128 tile, BK=64, 4 waves, 16x16x32 MFMA,
// global_load_lds(16B) both operands, linear LDS dest + inverse-XOR-swizzled
// source + swizzled ds_read (conflict-free b128). f32 epilogue.
__global__ void gemm_split(const uint16_t* __restrict__ A,
                           const uint16_t* __restrict__ B,
                           const float* __restrict__ grid,
                           float* __restrict__ C)
{
    if (detect_mode(grid) != MODE_F32) return;

    __shared__ uint16_t Alds[128 * 64];
    __shared__ uint16_t Blds[128 * 64];

    int t = threadIdx.x, l = t & 63, w = t >> 6;
    int bid = blockIdx.x;                      // 1024 wgs, bijective XCD swizzle
    int swz = (bid & 7) * 128 + (bid >> 3);
    int bm = swz >> 5, bn = swz & 31;
    size_t mbase = (size_t)bm * 128, nbase = (size_t)bn * 128;

    int lr8 = l >> 3, lc8 = l & 7, l15 = l & 15, lh = l >> 4;
    int wr = w >> 1, wc = w & 1;

    f32x4 acc[4][4] = {};

    for (int kt = 0; kt < K_IN / 64; ++kt) {
        __syncthreads();                       // prev iter's LDS reads done
        #pragma unroll
        for (int i = 0; i < 4; ++i) {
            int row = w * 32 + i * 8 + lr8;
            int cg  = lc8 ^ (row & 7);
            gload16(A + (mbase + row) * K_IN + kt * 64 + cg * 8,
                    &Alds[(w * 32 + i * 8) * 64]);
            gload16(B + (nbase + row) * K_IN + kt * 64 + cg * 8,
                    &Blds[(w * 32 + i * 8) * 64]);
        }
        __syncthreads();                       // vmcnt(0) drain: tiles ready

        #pragma unroll
        for (int ks = 0; ks < 2; ++ks) {
            bf16x8 af[4], bfr[4];
            #pragma unroll
            for (int i = 0; i < 4; ++i) {
                int ar = wr * 64 + i * 16 + l15;
                af[i] = *(const bf16x8*)&Alds[ar * 64 + (((ks << 2) | lh) ^ (ar & 7)) * 8];
            }
            #pragma unroll
            for (int j = 0; j < 4; ++j) {
                int br = wc * 64 + j * 16 + l15;
                bfr[j] = *(const bf16x8*)&Blds[br * 64 + (((ks << 2) | lh) ^ (br & 7)) * 8];
            }
            #pragma unroll
            for (int i = 0; i < 4; ++i)
                #pragma unroll
                for (int j = 0; j < 4; ++j)
                    acc[i][j] = __builtin_amdgcn_mfma_f32_16x16x32_bf16(
                        af[i], bfr[j], acc[i][j], 0, 0, 0);
        }
    }

    #pragma unroll
    for (int i = 0; i < 4; ++i)
        #pragma unroll
        for (int j = 0; j < 4; ++j) {
            size_t r0 = mbase + wr * 64 + i * 16 + lh * 4;
            size_t c0 = nbase + wc * 64 + j * 16 + l15;
            #pragma unroll
            for (int v = 0; v < 4; ++v)
                C[(r0 + v) * N_OUT + c0] = acc[i][j][v];
        }
}

// ===========================================================================
// FALLBACK / 16-BIT-WORLD PATHS (validated round 4)
// ===========================================================================
template<int MODE>
__global__ void fused16(const uint16_t* __restrict__ A,
                        const uint32_t* __restrict__ Q,
                        const uint32_t* __restrict__ grid,
                        const uint32_t* __restrict__ e81b,
                        uint16_t* __restrict__ C)
{
    if (detect_mode(grid) != MODE) return;

    __shared__ uint16_t Alds[128 * 64];
    __shared__ uint16_t Blds[128 * 64];
    __shared__ uint4 e8[256];

    int t = threadIdx.x;
    int l = t & 63, w = t >> 6;
    e8[t] = ((const uint4*)e81b)[t];

    int bid = blockIdx.x;
    int swz = (bid & 7) * 128 + (bid >> 3);
    int bm = swz >> 5, bn = swz & 31;
    size_t mbase = (size_t)bm * 128, nbase = (size_t)bn * 128;

    int lr8 = l >> 3, lc8 = l & 7, l15 = l & 15, lh = l >> 4;
    int wr = w >> 1, wc = w & 1;

    int rB = t >> 1, hB = t & 1;
    const uint32_t* qrow = Q + (nbase + rB) * 384;
    uint16_t* blds_row = &Blds[rB * 64];
    int r7 = rB & 7;

    h2 s16;
    { union { uint32_t u; h2 h; } c; c.u = 0x37D837D8u; s16 = c.h; }
    const float sbf = 0.490234375f;

    f32x4 acc[4][4] = {};
    __syncthreads();

    for (int kt = 0; kt < K_IN / 64; ++kt) {
        #pragma unroll
        for (int i = 0; i < 4; ++i) {
            int arow = w * 32 + i * 8 + lr8;
            gload16(A + (mbase + arow) * K_IN + kt * 64 + (lc8 ^ (arow & 7)) * 8,
                    &Alds[(w * 32 + i * 8) * 64]);
        }
        {
            const uint32_t* src = qrow + kt * 6 + hB * 3;
            uint32_t w0 = src[0], w1 = src[1], w2 = src[2];
            uint32_t code[4] = {
                w0 & 0xFFFFFFu,
                (w0 >> 24) | ((w1 & 0xFFFFu) << 8),
                (w1 >> 16) | ((w2 & 0xFFu) << 16),
                w2 >> 8
            };
            #pragma unroll
            for (int j = 0; j < 4; ++j) {
                uint4 g = ((const uint4*)grid)[code[j] >> 8];
                uint4 r = e8[code[j] & 255];
                uint32_t o[4];
                if constexpr (MODE == MODE_F16) {
                    o[0] = fma_h2(g.x, r.x, s16); o[1] = fma_h2(g.y, r.y, s16);
                    o[2] = fma_h2(g.z, r.z, s16); o[3] = fma_h2(g.w, r.w, s16);
                } else {
                    o[0] = fma_b2(g.x, r.x, sbf); o[1] = fma_b2(g.y, r.y, sbf);
                    o[2] = fma_b2(g.z, r.z, sbf); o[3] = fma_b2(g.w, r.w, sbf);
                }
                int cglob = hB * 4 + j;
                *(uint4*)&blds_row[(cglob ^ r7) * 8] = make_uint4(o[0], o[1], o[2], o[3]);
            }
        }
        __syncthreads();

        #pragma unroll
        for (int ks = 0; ks < 2; ++ks) {
            #pragma unroll
            for (int i = 0; i < 4; ++i) {
                int ar = wr * 64 + i * 16 + l15;
                const uint16_t* ap = &Alds[ar * 64 + (((ks << 2) | lh) ^ (ar & 7)) * 8];
                #pragma unroll
                for (int j = 0; j < 4; ++j) {
                    int br = wc * 64 + j * 16 + l15;
                    const uint16_t* bp = &Blds[br * 64 + (((ks << 2) | lh) ^ (br & 7)) * 8];
                    if constexpr (MODE == MODE_F16)
                        acc[i][j] = __builtin_amdgcn_mfma_f32_16x16x32_f16(
                            *(const f16x8*)ap, *(const f16x8*)bp, acc[i][j], 0, 0, 0);
                    else
                        acc[i][j] = __builtin_amdgcn_mfma_f32_16x16x32_bf16(
                            *(const bf16x8*)ap, *(const bf16x8*)bp, acc[i][j], 0, 0, 0);
                }
            }
        }
        __syncthreads();
    }

    #pragma unroll
    for (int i = 0; i < 4; ++i)
        #pragma unroll
        for (int j = 0; j < 4; ++j) {
            size_t r0 = mbase + wr * 64 + i * 16 + lh * 4;
            size_t c0 = nbase + wc * 64 + j * 16 + l15;
            #pragma unroll
            for (int v = 0; v < 4; ++v) {
                float x = acc[i][j][v];
                C[(r0 + v) * N_OUT + c0] = (MODE == MODE_F16) ? f2h(x) : f2b(x);
            }
        }
}

__global__ void fused32(const float* __restrict__ A,
                        const uint32_t* __restrict__ Q,
                        const float* __restrict__ grid,
                        const float* __restrict__ e81b,
                        float* __restrict__ C)
{
    if (detect_mode(grid) != MODE_F32) return;

    __shared__ uint16_t Alds[128 * 64];
    __shared__ uint16_t Blds[128 * 64];
    __shared__ float e8f[256 * 8];

    int t = threadIdx.x;
    int l = t & 63, w = t >> 6;
    #pragma unroll
    for (int i = 0; i < 8; ++i) e8f[t * 8 + i] = e81b[t * 8 + i];

    int bid = blockIdx.x;
    int swz = (bid & 7) * 128 + (bid >> 3);
    int bm = swz >> 5, bn = swz & 31;
    size_t mbase = (size_t)bm * 128, nbase = (size_t)bn * 128;

    int lr8 = l >> 3, lc8 = l & 7, l15 = l & 15, lh = l >> 4;
    int wr = w >> 1, wc = w & 1;

    int rB = t >> 1, hB = t & 1;
    const uint32_t* qrow = Q + (nbase + rB) * 384;
    uint16_t* blds_row = &Blds[rB * 64];
    int r7 = rB & 7;
    const float S = 1.0f / 2.04f;

    f32x4 acc[4][4] = {};
    __syncthreads();

    for (int kt = 0; kt < K_IN / 64; ++kt) {
        #pragma unroll
        for (int i = 0; i < 4; ++i) {
            int arow = w * 32 + i * 8 + lr8;
            const float* src = A + (mbase + arow) * (size_t)K_IN + kt * 64 + lc8 * 8;
            float4 f0 = ((const float4*)src)[0];
            float4 f1 = ((const float4*)src)[1];
            uint4 o = make_uint4(pk(f0.x, f0.y), pk(f0.z, f0.w),
                                 pk(f1.x, f1.y), pk(f1.z, f1.w));
            *(uint4*)&Alds[arow * 64 + (lc8 ^ (arow & 7)) * 8] = o;
        }
        {
            const uint32_t* src = qrow + kt * 6 + hB * 3;
            uint32_t w0 = src[0], w1 = src[1], w2 = src[2];
            uint32_t code[4] = {
                w0 & 0xFFFFFFu,
                (w0 >> 24) | ((w1 & 0xFFFFu) << 8),
                (w1 >> 16) | ((w2 & 0xFFu) << 16),
                w2 >> 8
            };
            #pragma unroll
            for (int j = 0; j < 4; ++j) {
                const float* gr = grid + (size_t)(code[j] >> 8) * 8;
                const float* rr = &e8f[(code[j] & 255u) * 8];
                float4 g0 = ((const float4*)gr)[0];
                float4 g1 = ((const float4*)gr)[1];
                uint4 o = make_uint4(
                    pk(g0.x + S * rr[0], g0.y + S * rr[1]),
                    pk(g0.z + S * rr[2], g0.w + S * rr[3]),
                    pk(g1.x + S * rr[4], g1.y + S * rr[5]),
                    pk(g1.z + S * rr[6], g1.w + S * rr[7]));
                int cglob = hB * 4 + j;
                *(uint4*)&blds_row[(cglob ^ r7) * 8] = o;
            }
        }
        __syncthreads();

        #pragma unroll
        for (int ks = 0; ks < 2; ++ks) {
            #pragma unroll
            for (int i = 0; i < 4; ++i) {
                int ar = wr * 64 + i * 16 + l15;
                const uint16_t* ap = &Alds[ar * 64 + (((ks << 2) | lh) ^ (ar & 7)) * 8];
                #pragma unroll
                for (int j = 0; j < 4; ++j) {
                    int br = wc * 64 + j * 16 + l15;
                    const uint16_t* bp = &Blds[br * 64 + (((ks << 2) | lh) ^ (br & 7)) * 8];
                    acc[i][j] = __builtin_amdgcn_mfma_f32_16x16x32_bf16(
                        *(const bf16x8*)ap, *(const bf16x8*)bp, acc[i][j], 0, 0, 0);
                }
            }
        }
        __syncthreads();
    }

    #pragma unroll
    for (int i = 0; i < 4; ++i)
        #pragma unroll
        for (int j = 0; j < 4; ++j) {
            size_t r0 = mbase + wr * 64 + i * 16 + lh * 4;
            size_t c0 = nbase + wc * 64 + j * 16 + l15;
            #pragma unroll
            for (int v = 0; v < 4; ++v)
                C[(r0 + v) * N_OUT + c0] = acc[i][j][v];
        }
}

extern "C" void kernel_launch(void* const* d_in, const int* in_sizes, int n_in,
                              void* d_out, int out_size, void* d_ws, size_t ws_size,
                              hipStream_t stream) {
    const void*     A    = d_in[0];
    const uint32_t* Q    = (const uint32_t*)d_in[1];
    const void*     grid = d_in[2];
    const void*     e81b = d_in[3];
    for (int i = 0; i < n_in; ++i) {
        if (in_sizes[i] == 16777216)      A    = d_in[i];
        else if (in_sizes[i] == 1572864)  Q    = (const uint32_t*)d_in[i];
        else if (in_sizes[i] == 524288)   grid = d_in[i];
        else if (in_sizes[i] == 2048)     e81b = d_in[i];
    }

    const bool split = ws_size >= (size_t)(64u << 20);   // 32 MB W + 32 MB A(bf16)

    if (split) {
        uint16_t* Wbf = (uint16_t*)d_ws;                  // [4096][4096] bf16
        uint16_t* Abf = (uint16_t*)d_ws + 16777216;       // [4096][4096] bf16
        cvtA_f32  <<<8192, 256, 0, stream>>>((const float*)A, (const float*)grid, Abf);
        decomp_f32<<<8192, 256, 0, stream>>>(Q, (const float*)grid, (const float*)e81b, Wbf);
        gemm_split<<<1024, 256, 0, stream>>>(Abf, Wbf, (const float*)grid, (float*)d_out);
        // 16-bit-world insurance (self-gated; no-ops in f32 world)
        fused16<MODE_F16><<<1024, 256, 0, stream>>>(
            (const uint16_t*)A, Q, (const uint32_t*)grid, (const uint32_t*)e81b,
            (uint16_t*)d_out);
        fused16<MODE_BF16><<<1024, 256, 0, stream>>>(
            (const uint16_t*)A, Q, (const uint32_t*)grid, (const uint32_t*)e81b,
            (uint16_t*)d_out);
    } else {
        fused16<MODE_F16><<<1024, 256, 0, stream>>>(
            (const uint16_t*)A, Q, (const uint32_t*)grid, (const uint32_t*)e81b,
            (uint16_t*)d_out);
        fused16<MODE_BF16><<<1024, 256, 0, stream>>>(
            (const uint16_t*)A, Q, (const uint32_t*)grid, (const uint32_t*)e81b,
            (uint16_t*)d_out);
        fused32<<<1024, 256, 0, stream>>>(
            (const float*)A, Q, (const float*)grid, (const float*)e81b,
            (float*)d_out);
    }
}